// Round 8
// baseline (272.036 us; speedup 1.0000x reference)
//
#include <hip/hip_runtime.h>
#include <math.h>

#define NN 100000
#define NE 1600000
#define C 128

#define TS 4096                       // edges per sort tile
#define NT ((NE + TS - 1) / TS)       // 391 tiles
#define BUK ((NN + 511) >> 9)         // 196 buckets of 512 nodes
#define NSC (BUK * NT)                // 76636 scan elements
#define NBS ((NSC + 2047) / 2048)     // 38 scan blocks (<=64)
#define PREP_BLKS (NN * C / 8 / 256)  // 6250
#define CONVW_BLKS (2 * C * C / 256)  // 128
#define GM 64                         // gemm rows per block

typedef __attribute__((ext_vector_type(8))) short          bf16x8;
typedef __attribute__((ext_vector_type(4))) float          f32x4;
typedef __attribute__((ext_vector_type(8))) unsigned short u16x8;
typedef unsigned short ushort_t;
typedef unsigned int   uint_t;

__device__ inline ushort_t f2bf(float f) {   // RTNE float -> bf16 bits
    union { float f; uint_t u; } a; a.f = f;
    uint_t r = a.u + 0x7fff + ((a.u >> 16) & 1);
    return (ushort_t)(r >> 16);
}

// =============== K1: merged setup (prep_xh+xt | conv_w | p1_hist) ============
// xh: [NN][256] bf16 (cols 0..127 = bf16(x), 128..255 = maxdiff, filled later)
// xt: [NN][128] u16, monotone-transformed bf16(x) for packed-min gathers
__global__ __launch_bounds__(256) void k_setup(
        const float* __restrict__ x, ushort_t* __restrict__ xh,
        ushort_t* __restrict__ xt,
        const float* __restrict__ W, ushort_t* __restrict__ Wt,
        const int* __restrict__ dst, int* __restrict__ tileHistT) {
    __shared__ int h[BUK];
    const int t  = threadIdx.x;
    const int bb = blockIdx.x;
    if (bb < PREP_BLKS) {                      // x -> bf16 rows of xh + xt
        int i = bb * 256 + t;                  // one thread per 8 floats
        int node = i >> 4;
        int c0   = (i & 15) * 8;
        const float4* xp = (const float4*)(x + (long)i * 8);
        float4 v0 = xp[0], v1 = xp[1];
        ushort_t o[8] = { f2bf(v0.x), f2bf(v0.y), f2bf(v0.z), f2bf(v0.w),
                          f2bf(v1.x), f2bf(v1.y), f2bf(v1.z), f2bf(v1.w) };
        ushort_t tt[8];
        #pragma unroll
        for (int j = 0; j < 8; ++j)
            tt[j] = (o[j] & 0x8000) ? (ushort_t)~o[j] : (ushort_t)(o[j] | 0x8000);
        *(bf16x8*)(xh + (long)node * 256 + c0) = *(bf16x8*)o;
        *(bf16x8*)(xt + (long)node * 128 + c0) = *(bf16x8*)tt;
    } else if (bb < PREP_BLKS + CONVW_BLKS) {  // W [256][128] -> Wt bf16 [128][256]
        int i = (bb - PREP_BLKS) * 256 + t;
        int k = i >> 7, n = i & 127;
        Wt[n * 256 + k] = f2bf(W[i]);
    } else {                                   // tile histogram over 196 buckets
        const int tile = bb - PREP_BLKS - CONVW_BLKS;
        for (int i = t; i < BUK; i += 256) h[i] = 0;
        __syncthreads();
        const int base = tile * TS;
        for (int i = t; i < TS; i += 256) {
            int e = base + i;
            if (e < NE) atomicAdd(&h[dst[e] >> 9], 1);
        }
        __syncthreads();
        for (int i = t; i < BUK; i += 256) tileHistT[i * NT + tile] = h[i];
    }
}

// ======================= scan over tile-hist =================================
__global__ __launch_bounds__(256) void scan_partial(const int* __restrict__ in,
                                                    int* __restrict__ out,
                                                    int* __restrict__ blocksums,
                                                    int n) {
    __shared__ int ts[256];
    const int t = threadIdx.x;
    const int base = blockIdx.x * 2048 + t * 8;
    int c[8];
    int s = 0;
    #pragma unroll
    for (int j = 0; j < 8; ++j) {
        int i = base + j;
        c[j] = (i < n) ? in[i] : 0;
        s += c[j];
    }
    ts[t] = s;
    __syncthreads();
    for (int off = 1; off < 256; off <<= 1) {
        int add = (t >= off) ? ts[t - off] : 0;
        __syncthreads();
        ts[t] += add;
        __syncthreads();
    }
    int run = (t == 0) ? 0 : ts[t - 1];
    #pragma unroll
    for (int j = 0; j < 8; ++j) {
        int i = base + j;
        if (i < n) out[i] = run;
        run += c[j];
    }
    if (t == 255) blocksums[blockIdx.x] = ts[255];
}

// wave-0 helper: exclusive scan of NBS blocksums into LDS bbase[64]
__device__ inline void scan_bsums_lds(const int* __restrict__ blocksums,
                                      int* bbase, int t) {
    if (t < 64) {
        int v = (t < NBS) ? blocksums[t] : 0;
        int incl = v;
        #pragma unroll
        for (int off = 1; off < 64; off <<= 1) {
            int nbr = __shfl_up(incl, off, 64);
            if (t >= off) incl += nbr;
        }
        bbase[t] = incl - v;
    }
}

// ======================= P3: coarse scatter of packed (local9|src17) =========
__global__ __launch_bounds__(256) void p3_scatter(const int* __restrict__ dst,
                                                  const int* __restrict__ src,
                                                  const int* __restrict__ tileScan,
                                                  const int* __restrict__ blocksums,
                                                  uint_t* __restrict__ coarse) {
    __shared__ int cur[BUK];
    __shared__ int bbase[64];
    const int t = threadIdx.x, tile = blockIdx.x;
    scan_bsums_lds(blocksums, bbase, t);
    __syncthreads();
    for (int i = t; i < BUK; i += 256) {
        int idx = i * NT + tile;
        cur[i] = tileScan[idx] + bbase[idx >> 11];
    }
    __syncthreads();
    const int base = tile * TS;
    for (int i = t; i < TS; i += 256) {
        int e = base + i;
        if (e < NE) {
            int d = dst[e];
            int p = atomicAdd(&cur[d >> 9], 1);
            coarse[p] = ((uint_t)(d & 511) << 17) | (uint_t)src[e];
        }
    }
}

// ======================= P4: per-bucket exact CSR ============================
__global__ __launch_bounds__(256) void p4_build(const uint_t* __restrict__ coarse,
                                                const int* __restrict__ tileScan,
                                                const int* __restrict__ blocksums,
                                                int* __restrict__ offs,
                                                int* __restrict__ ssrc) {
    __shared__ int cnt[512];
    __shared__ int ts[256];
    __shared__ int bbase[64];
    const int b = blockIdx.x, t = threadIdx.x;
    scan_bsums_lds(blocksums, bbase, t);
    const int n0 = b << 9;
    cnt[t] = 0; cnt[t + 256] = 0;
    __syncthreads();
    const int i0 = b * NT;
    const int bs = tileScan[i0] + bbase[i0 >> 11];
    int be;
    if (b == BUK - 1) be = NE;
    else { int i1 = (b + 1) * NT; be = tileScan[i1] + bbase[i1 >> 11]; }
    for (int i = bs + t; i < be; i += 256)
        atomicAdd(&cnt[(int)(coarse[i] >> 17)], 1);
    __syncthreads();
    int c0 = cnt[2 * t], c1 = cnt[2 * t + 1];
    ts[t] = c0 + c1;
    __syncthreads();
    for (int off = 1; off < 256; off <<= 1) {
        int add = (t >= off) ? ts[t - off] : 0;
        __syncthreads();
        ts[t] += add;
        __syncthreads();
    }
    int ex = (t == 0) ? 0 : ts[t - 1];
    int o0 = bs + ex, o1 = o0 + c0;
    cnt[2 * t] = o0; cnt[2 * t + 1] = o1;
    if (n0 + 2 * t < NN)     offs[n0 + 2 * t]     = o0;
    if (n0 + 2 * t + 1 < NN) offs[n0 + 2 * t + 1] = o1;
    if (b == BUK - 1 && t == 0) offs[NN] = NE;
    __syncthreads();
    for (int i = bs + t; i < be; i += 256) {
        uint_t pk = coarse[i];
        int p = atomicAdd(&cnt[(int)(pk >> 17)], 1);
        ssrc[p] = (int)(pk & 0x1FFFF);
    }
}

// ============ node min v3: packed v_pk_min_u16 on transformed gathers ========
__global__ __launch_bounds__(256) void node_min_v3(
        const int* __restrict__ offs, const int* __restrict__ ssrc,
        const ushort_t* __restrict__ xt, ushort_t* __restrict__ xh) {
    const int wid  = (blockIdx.x * 256 + threadIdx.x) >> 6;
    const int lane = threadIdx.x & 63;
    if (wid >= NN) return;
    const int g = lane >> 4;          // edge slot 0..3
    const int s = lane & 15;          // 16B chunk -> channels [8s..8s+8)
    const int beg = offs[wid], end = offs[wid + 1];
    const char* xb = (const char*)xt;
    u16x8 vm;
    #pragma unroll
    for (int j = 0; j < 8; ++j) vm[j] = 0xFFFFu;   // +inf in transformed space
    int i = beg;
    for (; i + 8 <= end; i += 8) {                 // 8 edges/iter (2 per slot)
        int e0 = ssrc[i + g];
        int e1 = ssrc[i + 4 + g];
        u16x8 a = *(const u16x8*)(xb + (long)e0 * 256 + s * 16);
        u16x8 bq = *(const u16x8*)(xb + (long)e1 * 256 + s * 16);
        vm = __builtin_elementwise_min(vm, a);
        vm = __builtin_elementwise_min(vm, bq);
    }
    for (; i < end; i += 4) {                      // masked tail
        int e = i + g;
        int idx = ssrc[(e < end) ? e : (end - 1)];
        u16x8 a = *(const u16x8*)(xb + (long)idx * 256 + s * 16);
        if (e < end) vm = __builtin_elementwise_min(vm, a);
    }
    // combine the 4 edge slots (packed shuffles)
    union { u16x8 v; uint_t u[4]; } cv, ov;
    cv.v = vm;
    #pragma unroll
    for (int j = 0; j < 4; ++j) ov.u[j] = __shfl_xor(cv.u[j], 16, 64);
    cv.v = __builtin_elementwise_min(cv.v, ov.v);
    #pragma unroll
    for (int j = 0; j < 4; ++j) ov.u[j] = __shfl_xor(cv.u[j], 32, 64);
    cv.v = __builtin_elementwise_min(cv.v, ov.v);

    if (g == 0) {                                  // 16 lanes write the row
        const bool has = end > beg;
        uint4 xd = *(const uint4*)((const char*)xh + (long)wid * 512 + s * 16);
        uint_t xu[4] = { xd.x, xd.y, xd.z, xd.w };
        uint4 o;
        uint_t* op = (uint_t*)&o;
        #pragma unroll
        for (int j = 0; j < 4; ++j) {
            ushort_t t0 = cv.v[2 * j], t1 = cv.v[2 * j + 1];
            ushort_t b0 = (t0 & 0x8000) ? (ushort_t)(t0 ^ 0x8000) : (ushort_t)~t0;
            ushort_t b1 = (t1 & 0x8000) ? (ushort_t)(t1 ^ 0x8000) : (ushort_t)~t1;
            float lo = has ? (__uint_as_float(xu[j] << 16)
                              - __uint_as_float((uint_t)b0 << 16)) : 0.0f;
            float hi = has ? (__uint_as_float(xu[j] & 0xffff0000u)
                              - __uint_as_float((uint_t)b1 << 16)) : 0.0f;
            op[j] = (uint_t)f2bf(lo) | ((uint_t)f2bf(hi) << 16);
        }
        *(uint4*)((char*)xh + (long)wid * 512 + 256 + s * 16) = o;
    }
}

// ======= MFMA GEMM v2: B fully in registers, per-wave 32-col slice ===========
__global__ __launch_bounds__(256) void gemm_mfma(
        const ushort_t* __restrict__ xh, const ushort_t* __restrict__ Wt,
        const float* __restrict__ b, float* __restrict__ out) {
    const int w    = threadIdx.x >> 6;
    const int l    = threadIdx.x & 63;
    const int wcol = w * 32;
    const int lr   = l & 15;
    const int kb   = (l >> 4) * 8;

    bf16x8 bb[2][8];
    float  bv[2];
    #pragma unroll
    for (int n = 0; n < 2; ++n) {
        int col = wcol + n * 16 + lr;
        bv[n] = b[col];
        const ushort_t* wp = Wt + (long)col * 256 + kb;
        #pragma unroll
        for (int k0 = 0; k0 < 8; ++k0)
            bb[n][k0] = *(const bf16x8*)(wp + k0 * 32);
    }

    const int mb0 = blockIdx.x * GM;
    #pragma unroll
    for (int mt = 0; mt < GM / 16; ++mt) {
        int mbase = mb0 + mt * 16;
        int arow = mbase + lr;
        if (arow >= NN) arow = NN - 1;
        const ushort_t* ap = xh + (long)arow * 256 + kb;
        bf16x8 a[8];
        #pragma unroll
        for (int k0 = 0; k0 < 8; ++k0) a[k0] = *(const bf16x8*)(ap + k0 * 32);

        f32x4 acc0 = (f32x4){0.f, 0.f, 0.f, 0.f};
        f32x4 acc1 = (f32x4){0.f, 0.f, 0.f, 0.f};
        #pragma unroll
        for (int k0 = 0; k0 < 8; ++k0) {
            acc0 = __builtin_amdgcn_mfma_f32_16x16x32_bf16(a[k0], bb[0][k0], acc0, 0, 0, 0);
            acc1 = __builtin_amdgcn_mfma_f32_16x16x32_bf16(a[k0], bb[1][k0], acc1, 0, 0, 0);
        }

        int rbase = mbase + ((l >> 4) << 2);
        int col0 = wcol + lr;
        #pragma unroll
        for (int j = 0; j < 4; ++j) {
            int r = rbase + j;
            if (r < NN) {
                out[(long)r * 128 + col0]      = fmaxf(acc0[j] + bv[0], 0.0f);
                out[(long)r * 128 + col0 + 16] = fmaxf(acc1[j] + bv[1], 0.0f);
            }
        }
    }
}

// ======================= zero-ws fallback ====================================
__global__ void init_neginf(float* __restrict__ p, int n) {
    int i = blockIdx.x * blockDim.x + threadIdx.x;
    if (i < n) p[i] = -INFINITY;
}

__device__ inline void amaxf(float* a, float v, float cur) {
    if (cur >= v) return;
    if (v >= 0.0f) atomicMax((int*)a, __float_as_int(v));
    else           atomicMin((unsigned int*)a, __float_as_uint(v));
}

__global__ __launch_bounds__(256) void edge_max(
        const float* __restrict__ x, const int* __restrict__ src,
        const int* __restrict__ dst, float* __restrict__ maxdiff) {
    long tid = (long)blockIdx.x * blockDim.x + threadIdx.x;
    int e = (int)(tid >> 5);
    if (e >= NE) return;
    int lane = (int)(tid & 31);
    int s = src[e], d = dst[e];
    int c0 = lane * 4;
    const float4 xd = *(const float4*)(x + (long)d * C + c0);
    const float4 xs = *(const float4*)(x + (long)s * C + c0);
    float4 df;
    df.x = xd.x - xs.x; df.y = xd.y - xs.y;
    df.z = xd.z - xs.z; df.w = xd.w - xs.w;
    float* o = maxdiff + (long)d * C + c0;
    float4 cur = *(const float4*)o;
    amaxf(o + 0, df.x, cur.x);
    amaxf(o + 1, df.y, cur.y);
    amaxf(o + 2, df.z, cur.z);
    amaxf(o + 3, df.w, cur.w);
}

#define TN 32
__global__ __launch_bounds__(256) void gemm_relu(
        const float* __restrict__ x, const float* __restrict__ W,
        const float* __restrict__ b, float* __restrict__ out) {
    __shared__ float h[TN][2 * C];
    const int nb = blockIdx.x * TN;
    const int t  = threadIdx.x;
    for (int i = t; i < TN * 2 * C / 4; i += 256) {
        int idx  = i * 4;
        int node = idx / (2 * C);
        int ci   = idx % (2 * C);
        float4 v;
        if (ci < C) {
            v = *(const float4*)(x + (long)(nb + node) * C + ci);
        } else {
            v = *(const float4*)(out + (long)(nb + node) * C + (ci - C));
            if (v.x == -INFINITY) v.x = 0.0f;
            if (v.y == -INFINITY) v.y = 0.0f;
            if (v.z == -INFINITY) v.z = 0.0f;
            if (v.w == -INFINITY) v.w = 0.0f;
        }
        *(float4*)&h[node][ci] = v;
    }
    __syncthreads();
    const int co = (t & 31) * 4;
    const int n0 = (t >> 5) * 4;
    float acc[4][4];
    #pragma unroll
    for (int i = 0; i < 4; ++i)
        #pragma unroll
        for (int j = 0; j < 4; ++j) acc[i][j] = 0.0f;
    for (int ci = 0; ci < 2 * C; ++ci) {
        float4 w = *(const float4*)(W + (long)ci * C + co);
        #pragma unroll
        for (int i = 0; i < 4; ++i) {
            float hv = h[n0 + i][ci];
            acc[i][0] = fmaf(hv, w.x, acc[i][0]);
            acc[i][1] = fmaf(hv, w.y, acc[i][1]);
            acc[i][2] = fmaf(hv, w.z, acc[i][2]);
            acc[i][3] = fmaf(hv, w.w, acc[i][3]);
        }
    }
    float4 bias = *(const float4*)(b + co);
    #pragma unroll
    for (int i = 0; i < 4; ++i) {
        float4 r;
        r.x = fmaxf(acc[i][0] + bias.x, 0.0f);
        r.y = fmaxf(acc[i][1] + bias.y, 0.0f);
        r.z = fmaxf(acc[i][2] + bias.z, 0.0f);
        r.w = fmaxf(acc[i][3] + bias.w, 0.0f);
        *(float4*)(out + (long)(nb + n0 + i) * C + co) = r;
    }
}

extern "C" void kernel_launch(void* const* d_in, const int* in_sizes, int n_in,
                              void* d_out, int out_size, void* d_ws, size_t ws_size,
                              hipStream_t stream) {
    const float* x   = (const float*)d_in[0];
    const float* W   = (const float*)d_in[1];
    const float* b   = (const float*)d_in[2];
    const int*   src = (const int*)d_in[3];
    const int*   dst = (const int*)d_in[4];
    float* out = (float*)d_out;

    // ws: blocksums[64]|pad[64]|tileScan[NSC]|offs[NN+1]|ssrc[NE] | xh | Wt
    // tileHistT aliases ssrc (dead before p4 writes ssrc).
    // coarse (NE uints) lives in d_out [0, 6.4MB); xt lives in d_out +8MB
    // (25.6MB) — both dead before gemm writes out.
    size_t ints_head = (size_t)128 + NSC + (NN + 1) + NE;
    size_t head_b    = ((ints_head * 4) + 255) & ~(size_t)255;
    size_t xh_b      = (size_t)NN * 256 * 2;          // 51.2 MB
    size_t wt_b      = (size_t)2 * C * C * 2;         // 64 KB
    size_t need      = head_b + xh_b + wt_b;

    if (ws_size >= need) {
        int* blocksums = (int*)d_ws;
        int* tileScan  = blocksums + 128;
        int* offs      = tileScan + NSC;
        int* ssrc      = offs + NN + 1;
        ushort_t* xh   = (ushort_t*)((char*)d_ws + head_b);
        ushort_t* Wt   = (ushort_t*)((char*)d_ws + head_b + xh_b);
        int*      tileHistT = ssrc;                       // alias (NSC <= NE)
        uint_t*   coarse    = (uint_t*)d_out;             // [0, 6.4MB)
        ushort_t* xt        = (ushort_t*)((char*)d_out + (8u << 20)); // 25.6MB

        k_setup<<<PREP_BLKS + CONVW_BLKS + NT, 256, 0, stream>>>(x, xh, xt, W, Wt, dst, tileHistT);
        scan_partial<<<NBS, 256, 0, stream>>>(tileHistT, tileScan, blocksums, NSC);
        p3_scatter<<<NT, 256, 0, stream>>>(dst, src, tileScan, blocksums, coarse);
        p4_build<<<BUK, 256, 0, stream>>>(coarse, tileScan, blocksums, offs, ssrc);
        node_min_v3<<<NN / 4, 256, 0, stream>>>(offs, ssrc, xt, xh);
        gemm_mfma<<<(NN + GM - 1) / GM, 256, 0, stream>>>(xh, Wt, b, out);
    } else {
        int n = NN * C;
        init_neginf<<<(n + 255) / 256, 256, 0, stream>>>(out, n);
        long threads = (long)NE * 32;
        edge_max<<<(int)((threads + 255) / 256), 256, 0, stream>>>(x, src, dst, out);
        gemm_relu<<<(NN + TN - 1) / TN, 256, 0, stream>>>(x, W, b, out);
    }
}